// Round 14
// baseline (173.542 us; speedup 1.0000x reference)
//
#include <hip/hip_runtime.h>
#include <hip/hip_bf16.h>
#include <math.h>

typedef __bf16 bf16_t;
typedef signed char i8_t;
typedef __attribute__((ext_vector_type(8))) __bf16 bf16x8;
typedef __attribute__((ext_vector_type(4))) __bf16 bf16x4;
typedef __attribute__((ext_vector_type(4))) float f32x4;
typedef __attribute__((ext_vector_type(4))) int i32x4;

typedef __attribute__((address_space(3))) void lds_void_t;
typedef const __attribute__((address_space(1))) void glb_void_t;
#define GLOAD_LDS(g, l) __builtin_amdgcn_global_load_lds((glb_void_t*)(g), (lds_void_t*)(l), 16, 0, 0)

#define MFMA16(a,b,c) __builtin_amdgcn_mfma_f32_16x16x32_bf16(a,b,c,0,0,0)
#define MFMAI8(a,b,c) __builtin_amdgcn_mfma_i32_16x16x64_i8(a,b,c,0,0,0)

#if __has_builtin(__builtin_amdgcn_exp2f)
#define EXP2F(x) __builtin_amdgcn_exp2f(x)
#else
#define EXP2F(x) exp2f(x)
#endif

static constexpr int TSEQ = 2048;
static constexpr int CDIM = 1024;
#define NEG_BIG (-1.0e30f)
// 0.125 * log2(e): baked into Q so scores are already in exp2 domain
#define Q_PRESCALE 0.18033688011112042f
// (2/64) * log2(10000): RoPE inv-freq exponent step
#define ROPE_C 0.41524101190971284f

// ---------------- weight scale partials: mean|W| (fp64, deterministic) ----------------
__global__ __launch_bounds__(256) void wreduce(const float* __restrict__ W0, const float* __restrict__ W1,
                                               const float* __restrict__ W2, const float* __restrict__ W3,
                                               double* __restrict__ partial) {
  int w = blockIdx.x >> 6, b = blockIdx.x & 63;
  const float* W = (w==0)?W0:(w==1)?W1:(w==2)?W2:W3;
  const float* base = W + (size_t)b * 16384;
  double s = 0.0;
  for (int i = threadIdx.x * 4; i < 16384; i += 1024) {
    float4 v = *(const float4*)(base + i);
    s += (double)fabsf(v.x) + (double)fabsf(v.y) + (double)fabsf(v.z) + (double)fabsf(v.w);
  }
  #pragma unroll
  for (int off = 1; off < 64; off <<= 1) s += __shfl_xor(s, off);
  __shared__ double red[4];
  if ((threadIdx.x & 63) == 0) red[threadIdx.x >> 6] = s;
  __syncthreads();
  if (threadIdx.x == 0) partial[blockIdx.x] = red[0] + red[1] + red[2] + red[3];
}

// ---- prep: wquant->i8 (0..4095) + actquant(x)->i8 (4096..8191) + rope table (8192..8447) ----
__global__ __launch_bounds__(256) void prep(const float* __restrict__ W0, const float* __restrict__ W1,
                                            const float* __restrict__ W2, const float* __restrict__ W3,
                                            const double* __restrict__ partial, float* __restrict__ wscale,
                                            i8_t* __restrict__ wq_all,
                                            const float* __restrict__ xg, i8_t* __restrict__ xqg,
                                            float* __restrict__ rowfac, float2* __restrict__ ropetab) {
  int bid = blockIdx.x;
  if (bid < 4096) {
    int w = bid >> 10;
    double ssum = 0.0;
    for (int i = 0; i < 64; ++i) ssum += partial[w * 64 + i];
    float s = fmaxf((float)(ssum * (1.0 / 1048576.0)), 1e-5f);
    if ((bid & 1023) == 0 && threadIdx.x == 0) wscale[w] = s;
    const float* W = (w==0)?W0:(w==1)?W1:(w==2)?W2:W3;
    int off = ((bid & 1023) * 256 + threadIdx.x) * 4;
    float4 v = *(const float4*)(W + off);
    char4 q;
    q.x = (i8_t)(int)fminf(fmaxf(rintf(v.x / s), -1.f), 1.f);
    q.y = (i8_t)(int)fminf(fmaxf(rintf(v.y / s), -1.f), 1.f);
    q.z = (i8_t)(int)fminf(fmaxf(rintf(v.z / s), -1.f), 1.f);
    q.w = (i8_t)(int)fminf(fmaxf(rintf(v.w / s), -1.f), 1.f);
    *(char4*)(wq_all + (size_t)w * 1048576 + off) = q;
  } else if (bid < 8192) {
    int r = bid - 4096;
    float4 v = *(const float4*)(xg + (size_t)r * 1024 + threadIdx.x * 4);
    float mx = fmaxf(fmaxf(fabsf(v.x), fabsf(v.y)), fmaxf(fabsf(v.z), fabsf(v.w)));
    #pragma unroll
    for (int off = 1; off < 64; off <<= 1) mx = fmaxf(mx, __shfl_xor(mx, off));
    __shared__ float red[4];
    if ((threadIdx.x & 63) == 0) red[threadIdx.x >> 6] = mx;
    __syncthreads();
    mx = fmaxf(fmaxf(red[0], red[1]), fmaxf(red[2], red[3]));
    mx = fmaxf(mx, 1e-5f);
    float scale = 127.0f / mx;
    if (threadIdx.x == 0) rowfac[r] = mx * (1.0f / 127.0f);
    char4 q;
    q.x = (i8_t)(int)fminf(fmaxf(rintf(v.x * scale), -128.f), 127.f);
    q.y = (i8_t)(int)fminf(fmaxf(rintf(v.y * scale), -128.f), 127.f);
    q.z = (i8_t)(int)fminf(fmaxf(rintf(v.z * scale), -128.f), 127.f);
    q.w = (i8_t)(int)fminf(fmaxf(rintf(v.w * scale), -128.f), 127.f);
    *(char4*)(xqg + (size_t)r * 1024 + threadIdx.x * 4) = q;
  } else {
    int t = (bid - 8192) * 8 + (threadIdx.x >> 5);
    int ii = threadIdx.x & 31;
    float ang = (float)t * exp2f(-(float)ii * ROPE_C);
    float sn, cs;
    sincosf(ang, &sn, &cs);
    ropetab[t * 32 + ii] = make_float2(cs, sn);
  }
}

// ---- y-path act quant: combine bf16 parity partials (y0+y1)/(d0+d1), then row quant -> i8 ----
__global__ __launch_bounds__(256) void actquant(const bf16_t* __restrict__ yf0, const bf16_t* __restrict__ yf1,
                                                const float* __restrict__ den0, const float* __restrict__ den1,
                                                i8_t* __restrict__ xqg, float* __restrict__ rowfac) {
  int r = blockIdx.x;
  int b = r >> 11, t = r & 2047;
  int h = threadIdx.x >> 4;                       // (tid*4)>>6
  size_t idx = (size_t)r * 1024 + threadIdx.x * 4;
  bf16x4 u0 = *(const bf16x4*)(yf0 + idx);
  bf16x4 u1 = *(const bf16x4*)(yf1 + idx);
  size_t di = (size_t)(b * 16 + h) * 2048 + t;
  float inv = 1.0f / (den0[di] + den1[di]);
  float4 v;
  v.x = ((float)u0[0] + (float)u1[0]) * inv;
  v.y = ((float)u0[1] + (float)u1[1]) * inv;
  v.z = ((float)u0[2] + (float)u1[2]) * inv;
  v.w = ((float)u0[3] + (float)u1[3]) * inv;
  float mx = fmaxf(fmaxf(fabsf(v.x), fabsf(v.y)), fmaxf(fabsf(v.z), fabsf(v.w)));
  #pragma unroll
  for (int off = 1; off < 64; off <<= 1) mx = fmaxf(mx, __shfl_xor(mx, off));
  __shared__ float red[4];
  if ((threadIdx.x & 63) == 0) red[threadIdx.x >> 6] = mx;
  __syncthreads();
  mx = fmaxf(fmaxf(red[0], red[1]), fmaxf(red[2], red[3]));
  mx = fmaxf(mx, 1e-5f);
  float scale = 127.0f / mx;
  if (threadIdx.x == 0) rowfac[r] = mx * (1.0f / 127.0f);
  char4 q;
  q.x = (i8_t)(int)fminf(fmaxf(rintf(v.x * scale), -128.f), 127.f);
  q.y = (i8_t)(int)fminf(fmaxf(rintf(v.y * scale), -128.f), 127.f);
  q.z = (i8_t)(int)fminf(fmaxf(rintf(v.z * scale), -128.f), 127.f);
  q.w = (i8_t)(int)fminf(fmaxf(rintf(v.w * scale), -128.f), 127.f);
  *(char4*)(xqg + (size_t)r * 1024 + threadIdx.x * 4) = q;
}

// ---------------- QKV GEMM, i8 MFMA K=64: double-buffered 2-phase pipeline + XCD-local panels ----------------
// 1-D grid 768, T1 remap: xcd = bid&7 owns 3 (y,z) pairs x 32 m-tiles, so each 128KB weight
// panel is read by exactly ONE XCD and stays in its 4MB L2 -> panel re-reads become ~200cyc
// L2 hits instead of cross-XCD/HBM (~900cyc). Latency-bound kernel -> shorter load latency
// directly shortens the per-iteration serial chain. Per-block work unchanged.
__global__ __launch_bounds__(256) void gemm_qkv(const i8_t* __restrict__ xq, const i8_t* __restrict__ wq_all,
                                                const float* __restrict__ wscale, const float* __restrict__ rowfac,
                                                const float2* __restrict__ ropetab,
                                                bf16_t* __restrict__ qb, bf16_t* __restrict__ kb,
                                                bf16_t* __restrict__ vtb) {
  const int bid = blockIdx.x;               // 0..767
  const int xcd = bid & 7;
  const int g   = bid >> 3;                 // 0..95
  const int pair = xcd * 3 + (g >> 5);      // 0..23  (3 pairs per XCD)
  const int xblk = g & 31;                  // 0..31
  const int z  = pair >> 3;                 // 0..2
  const int yb = pair & 7;                  // 0..7
  const i8_t* Bw = wq_all + (size_t)z * 1048576;
  const int m0 = xblk * 128, n0 = yb * 128;
  const int tid = threadIdx.x;
  const int wave = tid >> 6, lane = tid & 63, quad = lane >> 4, l16 = lane & 15;
  const int wm = wave >> 1, wn = wave & 1;
  __shared__ __align__(16) i8_t As[2][128 * 64];
  __shared__ __align__(16) i8_t Bs[2][128 * 64];
  i32x4 zero = {0, 0, 0, 0};
  i32x4 acc[4][4];
  #pragma unroll
  for (int i = 0; i < 4; ++i)
    #pragma unroll
    for (int j = 0; j < 4; ++j) acc[i][j] = zero;

  const int row_s = tid >> 2;
  const int cg16 = (((tid & 3) - (row_s >> 1)) & 3) * 16;   // swizzled global 16B-block (bytes)
  const int sw16 = ((quad + (l16 >> 1)) & 3) * 16;          // swizzled frag slot (bytes)

  // prologue: stage kt=0 into buffer 0
  #pragma unroll
  for (int v2 = 0; v2 < 2; ++v2) {
    int v = tid + v2 * 256;
    int row = row_s + v2 * 64;
    GLOAD_LDS(&xq[(size_t)(m0 + row) * 1024 + cg16], &As[0][v * 16]);
    GLOAD_LDS(&Bw[(size_t)(n0 + row) * 1024 + cg16], &Bs[0][v * 16]);
  }
  __syncthreads();   // drains vmcnt(0): buffer 0 ready

  #pragma unroll 2
  for (int kt = 0; kt < 16; ++kt) {
    const int cur = kt & 1;
    if (kt < 15) {
      #pragma unroll
      for (int v2 = 0; v2 < 2; ++v2) {
        int v = tid + v2 * 256;
        int row = row_s + v2 * 64;
        GLOAD_LDS(&xq[(size_t)(m0 + row) * 1024 + (kt + 1) * 64 + cg16], &As[cur ^ 1][v * 16]);
        GLOAD_LDS(&Bw[(size_t)(n0 + row) * 1024 + (kt + 1) * 64 + cg16], &Bs[cur ^ 1][v * 16]);
      }
    }
    i32x4 af[4], bfr[4];
    #pragma unroll
    for (int i = 0; i < 4; ++i) af[i] = *(const i32x4*)&As[cur][(wm * 64 + i * 16 + l16) * 64 + sw16];
    #pragma unroll
    for (int j = 0; j < 4; ++j) bfr[j] = *(const i32x4*)&Bs[cur][(wn * 64 + j * 16 + l16) * 64 + sw16];
    if (z == 2) {
      #pragma unroll
      for (int i = 0; i < 4; ++i)
        #pragma unroll
        for (int j = 0; j < 4; ++j) acc[i][j] = MFMAI8(bfr[i], af[j], acc[i][j]);  // C^T
    } else {
      #pragma unroll
      for (int i = 0; i < 4; ++i)
        #pragma unroll
        for (int j = 0; j < 4; ++j) acc[i][j] = MFMAI8(af[i], bfr[j], acc[i][j]);
    }
    __syncthreads();  // next-buffer loads drained; cur buffer free for kt+2 staging
  }
  float ws = wscale[z] * (z == 0 ? Q_PRESCALE : 1.0f);
  if (z <= 1) {
    bf16_t* dst = (z == 0) ? qb : kb;
    const int h = (n0 >> 6) + wn;
    #pragma unroll
    for (int i = 0; i < 4; ++i) {
      #pragma unroll
      for (int r = 0; r < 4; ++r) {
        int m = m0 + wm * 64 + i * 16 + quad * 4 + r;
        float rf = rowfac[m] * ws;
        int b = m >> 11, t = m & 2047;
        bf16_t* drow = dst + (((size_t)b * 16 + h) * 2048 + t) * 64;
        #pragma unroll
        for (int j = 0; j < 2; ++j) {
          int dd1 = j * 16 + l16;
          float2 cs2 = ropetab[t * 32 + dd1];
          float v1 = (float)acc[i][j][r] * rf;
          float v2 = (float)acc[i][j + 2][r] * rf;
          drow[dd1]      = (bf16_t)(v1 * cs2.x - v2 * cs2.y);
          drow[dd1 + 32] = (bf16_t)(v1 * cs2.y + v2 * cs2.x);
        }
      }
    }
  } else {
    // acc is C^T: row = n (head dim), col = m (time)
    const int b = m0 >> 11;
    const int tbase = (m0 & 2047) + wm * 64;
    float rfj[4];
    #pragma unroll
    for (int j = 0; j < 4; ++j) rfj[j] = rowfac[m0 + wm * 64 + j * 16 + l16] * ws;
    #pragma unroll
    for (int i = 0; i < 4; ++i) {
      #pragma unroll
      for (int r = 0; r < 4; ++r) {
        int nrow = n0 + wn * 64 + i * 16 + quad * 4 + r;
        int h = nrow >> 6, dd = nrow & 63;
        bf16_t* vrow = vtb + (((size_t)b * 16 + h) * 64 + dd) * 2048 + tbase;
        #pragma unroll
        for (int j = 0; j < 4; ++j) vrow[j * 16 + l16] = (bf16_t)((float)acc[i][j][r] * rfj[j]);
      }
    }
  }
}

// ---------------- output GEMM (i8 MFMA, 2-phase pipeline) + XCD-local Wo panels ----------------
// 1-D grid 256, y = bid&7: all 32 m-tiles of an n-panel on one XCD -> Wo panel L2-local.
__global__ __launch_bounds__(256) void gemm_out(const i8_t* __restrict__ yq, const i8_t* __restrict__ wo,
                                                const float* __restrict__ wscale, const float* __restrict__ rowfac,
                                                float* __restrict__ out) {
  const int bid = blockIdx.x;               // 0..255
  const int m0 = (bid >> 3) * 128, n0 = (bid & 7) * 128;
  const int tid = threadIdx.x;
  const int wave = tid >> 6, lane = tid & 63, quad = lane >> 4, l16 = lane & 15;
  const int wm = wave >> 1, wn = wave & 1;
  __shared__ __align__(16) i8_t As[2][128 * 64];
  __shared__ __align__(16) i8_t Bs[2][128 * 64];
  i32x4 zero = {0, 0, 0, 0};
  i32x4 acc[4][4];
  #pragma unroll
  for (int i = 0; i < 4; ++i)
    #pragma unroll
    for (int j = 0; j < 4; ++j) acc[i][j] = zero;

  const int row_s = tid >> 2;
  const int cg16 = (((tid & 3) - (row_s >> 1)) & 3) * 16;
  const int sw16 = ((quad + (l16 >> 1)) & 3) * 16;

  #pragma unroll
  for (int v2 = 0; v2 < 2; ++v2) {
    int v = tid + v2 * 256;
    int row = row_s + v2 * 64;
    GLOAD_LDS(&yq[(size_t)(m0 + row) * 1024 + cg16], &As[0][v * 16]);
    GLOAD_LDS(&wo[(size_t)(n0 + row) * 1024 + cg16], &Bs[0][v * 16]);
  }
  __syncthreads();

  #pragma unroll 2
  for (int kt = 0; kt < 16; ++kt) {
    const int cur = kt & 1;
    if (kt < 15) {
      #pragma unroll
      for (int v2 = 0; v2 < 2; ++v2) {
        int v = tid + v2 * 256;
        int row = row_s + v2 * 64;
        GLOAD_LDS(&yq[(size_t)(m0 + row) * 1024 + (kt + 1) * 64 + cg16], &As[cur ^ 1][v * 16]);
        GLOAD_LDS(&wo[(size_t)(n0 + row) * 1024 + (kt + 1) * 64 + cg16], &Bs[cur ^ 1][v * 16]);
      }
    }
    i32x4 af[4], bfr[4];
    #pragma unroll
    for (int i = 0; i < 4; ++i) af[i] = *(const i32x4*)&As[cur][(wm * 64 + i * 16 + l16) * 64 + sw16];
    #pragma unroll
    for (int j = 0; j < 4; ++j) bfr[j] = *(const i32x4*)&Bs[cur][(wn * 64 + j * 16 + l16) * 64 + sw16];
    #pragma unroll
    for (int i = 0; i < 4; ++i)
      #pragma unroll
      for (int j = 0; j < 4; ++j) acc[i][j] = MFMAI8(af[i], bfr[j], acc[i][j]);
    __syncthreads();
  }
  float ws = wscale[3];
  #pragma unroll
  for (int i = 0; i < 4; ++i) {
    #pragma unroll
    for (int r = 0; r < 4; ++r) {
      int m = m0 + wm * 64 + i * 16 + quad * 4 + r;
      float rf = rowfac[m] * ws;
      #pragma unroll
      for (int j = 0; j < 4; ++j) {
        int n = n0 + wn * 64 + j * 16 + l16;
        out[(size_t)m * 1024 + n] = (float)acc[i][j][r] * rf;
      }
    }
  }
}

// ---------------- flash attention: parity-split kc, 512 duration-uniform blocks ----------------
// Numerator partials stored as bf16 (same exponent range as f32 - no overflow risk; the
// 2^-9 mantissa loss is far below actquant's 1/127 quant granularity).
__global__ __launch_bounds__(512) void flash_attn(const bf16_t* __restrict__ qg, const bf16_t* __restrict__ kg,
                                                  const bf16_t* __restrict__ vtg,
                                                  bf16_t* __restrict__ yf0, bf16_t* __restrict__ yf1,
                                                  float* __restrict__ den0, float* __restrict__ den1) {
  const int lid = (int)blockIdx.y * 8 + (int)blockIdx.x;  // 0..511
  const int par = (lid >> 3) & 1;
  const int p   = (lid >> 4) & 7;
  const int bh  = (lid & 7) * 4 + (lid >> 7);
  bf16_t* __restrict__ yo = par ? yf1 : yf0;
  float* __restrict__ dn = par ? den1 : den0;
  const int tid = threadIdx.x;        // 0..511
  const int wave = tid >> 6, lane = tid & 63;
  const int quad = lane >> 4, l16 = lane & 15;

  __shared__ __align__(16) bf16_t Kb[2][64 * 64];
  __shared__ __align__(16) bf16_t Vb[2][64 * 64];
  __shared__ __align__(16) bf16_t Pl[8][16 * 72];

  const int b = bh >> 4, h = bh & 15;
  bf16_t* Pw = &Pl[wave][0];

  const int r0 = tid >> 3, cblk = tid & 7;
  const int ldsOff0 = r0 * 64 + ((cblk ^ (r0 & 7)) * 8);
  const size_t bhbase = (size_t)bh * 131072;
  const bf16_t* kbase0 = kg + bhbase + r0 * 64 + cblk * 8;    // + kc*4096
  const bf16_t* vbase0 = vtg + bhbase + r0 * 2048 + cblk * 8; // + kc*64

  int kf_off[4][2];
  #pragma unroll
  for (int n = 0; n < 4; ++n)
    #pragma unroll
    for (int c = 0; c < 2; ++c)
      kf_off[n][c] = (n * 16 + l16) * 64 + (((c * 4 + quad) ^ (l16 & 7)) * 8);

  bf16x8 ones;
  #pragma unroll
  for (int j = 0; j < 8; ++j) ones[j] = (bf16_t)1.0f;
  f32x4 zero = {0.f, 0.f, 0.f, 0.f};

  bf16x8 kpre = *(const bf16x8*)(kbase0 + par * 4096);
  bf16x8 vpre = *(const bf16x8*)(vbase0 + par * 64);

  int cum = 0;
  #pragma unroll 1
  for (int tsel = 0; tsel < 2; ++tsel) {
    const int qt = tsel ? (15 - p) : p;
    const int kcmax = 2 * qt + 1;                 // par <= kcmax always (kcmax >= 1)
    const int qbw = qt * 128 + wave * 16;

    const bf16_t* qrowp = qg + ((size_t)bh * TSEQ + qbw + l16) * 64;
    bf16x8 aq0 = *(const bf16x8*)(qrowp + quad * 8);
    bf16x8 aq1 = *(const bf16x8*)(qrowp + 32 + quad * 8);

    f32x4 o[4], o5;
    #pragma unroll
    for (int i = 0; i < 4; ++i) o[i] = zero;
    o5 = zero;

    #pragma unroll 1
    for (int kc = par; kc <= kcmax; kc += 2, ++cum) {
      const int buf = cum & 1;
      bf16_t* Kt = &Kb[buf][0];
      bf16_t* Vt = &Vb[buf][0];
      *(bf16x8*)&Kt[ldsOff0] = kpre;
      *(bf16x8*)&Vt[ldsOff0] = vpre;
      __syncthreads();
      int nkc = (kc + 2 <= kcmax) ? (kc + 2) : ((tsel == 0) ? par : -1);
      if (nkc >= 0) {
        kpre = *(const bf16x8*)(kbase0 + nkc * 4096);
        vpre = *(const bf16x8*)(vbase0 + nkc * 64);
      }

      // wave's 16 q-rows entirely below this k-chunk: contribution is exactly zero.
      if (kc * 64 > qbw + 15) continue;

      f32x4 s[4];
      __builtin_amdgcn_s_setprio(1);
      #pragma unroll
      for (int n = 0; n < 4; ++n) {
        bf16x8 bk0 = *(const bf16x8*)&Kt[kf_off[n][0]];
        bf16x8 bk1 = *(const bf16x8*)&Kt[kf_off[n][1]];
        s[n] = MFMA16(aq1, bk1, MFMA16(aq0, bk0, zero));
      }
      __builtin_amdgcn_s_setprio(0);
      if (kc * 64 + 63 > qbw) {
        #pragma unroll
        for (int n = 0; n < 4; ++n)
          #pragma unroll
          for (int r = 0; r < 4; ++r) {
            int kpos = kc * 64 + n * 16 + l16;
            int qpos = qbw + quad * 4 + r;
            if (kpos > qpos) s[n][r] = NEG_BIG;
          }
      }
      #pragma unroll
      for (int n = 0; n < 4; ++n)
        #pragma unroll
        for (int r = 0; r < 4; ++r)
          Pw[(quad * 4 + r) * 72 + n * 16 + l16] = (bf16_t)EXP2F(s[n][r]);

      bf16x8 ap0 = *(const bf16x8*)&Pw[l16 * 72 + quad * 8];
      bf16x8 ap1 = *(const bf16x8*)&Pw[l16 * 72 + 32 + quad * 8];
      __builtin_amdgcn_s_setprio(1);
      #pragma unroll
      for (int nh = 0; nh < 4; ++nh) {
        bf16x8 bv0 = *(const bf16x8*)&Vt[kf_off[nh][0]];
        bf16x8 bv1 = *(const bf16x8*)&Vt[kf_off[nh][1]];
        o[nh] = MFMA16(ap1, bv1, MFMA16(ap0, bv0, o[nh]));
      }
      o5 = MFMA16(ap1, ones, MFMA16(ap0, ones, o5));
      __builtin_amdgcn_s_setprio(0);
    }

    // write un-normalized partial numerator (bf16) + denominator (f32) for this parity
    #pragma unroll
    for (int r = 0; r < 4; ++r) {
      int t = qbw + quad * 4 + r;
      bf16_t* yrow = yo + ((size_t)b * TSEQ + t) * CDIM + h * 64;
      #pragma unroll
      for (int nh = 0; nh < 4; ++nh) yrow[nh * 16 + l16] = (bf16_t)o[nh][r];
      if (l16 == 0) dn[(size_t)bh * TSEQ + t] = o5[r];
    }
  }
}

extern "C" void kernel_launch(void* const* d_in, const int* in_sizes, int n_in,
                              void* d_out, int out_size, void* d_ws, size_t ws_size,
                              hipStream_t stream) {
  const float* x  = (const float*)d_in[0];
  const float* Wq = (const float*)d_in[1];
  const float* Wk = (const float*)d_in[2];
  const float* Wv = (const float*)d_in[3];
  const float* Wo = (const float*)d_in[4];
  float* out = (float*)d_out;   // reference output dtype is float32

  char* ws = (char*)d_ws;
  double* wpartial = (double*)(ws);                  // 256 f64
  float* wscale   = (float*)(ws + 4096);             // 4 f32
  float* rowfacx  = (float*)(ws + 8192);             // 4096 f32
  float* rowfacy  = (float*)(ws + 8192 + 16384);     // 4096 f32
  i8_t* wq_all    = (i8_t*)(ws + 65536);             // 4M i8 = 4MB
  i8_t* xq        = wq_all + 4194304;                // 4MB (aliased as yq later)
  bf16_t* qb      = (bf16_t*)(xq + 4194304);         // 8MB
  bf16_t* kb      = qb + 4194304;                    // 8MB
  bf16_t* vtb     = kb + 4194304;                    // 8MB, d-major V
  bf16_t* yf0     = vtb + 4194304;                   // 8MB (even-parity numerator, bf16)
  bf16_t* yf1     = yf0 + 4194304;                   // 8MB (odd-parity numerator, bf16)
  float2* ropetab = (float2*)(yf1 + 4194304);        // 512KB
  float*  den0    = (float*)((char*)ropetab + 524288); // 256KB
  float*  den1    = den0 + 65536;                    // 256KB
  i8_t* yq        = xq;                              // alias: xq dead after gemm_qkv

  wreduce<<<256, 256, 0, stream>>>(Wq, Wk, Wv, Wo, wpartial);
  prep<<<8448, 256, 0, stream>>>(Wq, Wk, Wv, Wo, wpartial, wscale, wq_all, x, xq, rowfacx, ropetab);
  gemm_qkv<<<768, 256, 0, stream>>>(xq, wq_all, wscale, rowfacx, ropetab, qb, kb, vtb);
  flash_attn<<<dim3(8, 64), 512, 0, stream>>>(qb, kb, vtb, yf0, yf1, den0, den1);
  actquant<<<4096, 256, 0, stream>>>(yf0, yf1, den0, den1, yq, rowfacy);
  gemm_out<<<256, 256, 0, stream>>>(yq, wq_all + 3 * 1048576, wscale, rowfacy, out);
}

// Round 15
// 167.256 us; speedup vs baseline: 1.0376x; 1.0376x over previous
//
#include <hip/hip_runtime.h>
#include <hip/hip_bf16.h>
#include <math.h>

typedef __bf16 bf16_t;
typedef signed char i8_t;
typedef __attribute__((ext_vector_type(8))) __bf16 bf16x8;
typedef __attribute__((ext_vector_type(4))) __bf16 bf16x4;
typedef __attribute__((ext_vector_type(4))) float f32x4;
typedef __attribute__((ext_vector_type(4))) int i32x4;

typedef __attribute__((address_space(3))) void lds_void_t;
typedef const __attribute__((address_space(1))) void glb_void_t;
#define GLOAD_LDS(g, l) __builtin_amdgcn_global_load_lds((glb_void_t*)(g), (lds_void_t*)(l), 16, 0, 0)

#define MFMA16(a,b,c) __builtin_amdgcn_mfma_f32_16x16x32_bf16(a,b,c,0,0,0)
#define MFMAI8(a,b,c) __builtin_amdgcn_mfma_i32_16x16x64_i8(a,b,c,0,0,0)

#if __has_builtin(__builtin_amdgcn_exp2f)
#define EXP2F(x) __builtin_amdgcn_exp2f(x)
#else
#define EXP2F(x) exp2f(x)
#endif

static constexpr int TSEQ = 2048;
static constexpr int CDIM = 1024;
#define NEG_BIG (-1.0e30f)
// 0.125 * log2(e): baked into Q so scores are already in exp2 domain
#define Q_PRESCALE 0.18033688011112042f
// (2/64) * log2(10000): RoPE inv-freq exponent step
#define ROPE_C 0.41524101190971284f

// ---------------- weight scale partials: mean|W| (fp64, deterministic) ----------------
__global__ __launch_bounds__(256) void wreduce(const float* __restrict__ W0, const float* __restrict__ W1,
                                               const float* __restrict__ W2, const float* __restrict__ W3,
                                               double* __restrict__ partial) {
  int w = blockIdx.x >> 6, b = blockIdx.x & 63;
  const float* W = (w==0)?W0:(w==1)?W1:(w==2)?W2:W3;
  const float* base = W + (size_t)b * 16384;
  double s = 0.0;
  for (int i = threadIdx.x * 4; i < 16384; i += 1024) {
    float4 v = *(const float4*)(base + i);
    s += (double)fabsf(v.x) + (double)fabsf(v.y) + (double)fabsf(v.z) + (double)fabsf(v.w);
  }
  #pragma unroll
  for (int off = 1; off < 64; off <<= 1) s += __shfl_xor(s, off);
  __shared__ double red[4];
  if ((threadIdx.x & 63) == 0) red[threadIdx.x >> 6] = s;
  __syncthreads();
  if (threadIdx.x == 0) partial[blockIdx.x] = red[0] + red[1] + red[2] + red[3];
}

// ---- prep: wquant->i8 (0..4095) + actquant(x)->i8 (4096..8191) + rope table (8192..8447) ----
__global__ __launch_bounds__(256) void prep(const float* __restrict__ W0, const float* __restrict__ W1,
                                            const float* __restrict__ W2, const float* __restrict__ W3,
                                            const double* __restrict__ partial, float* __restrict__ wscale,
                                            i8_t* __restrict__ wq_all,
                                            const float* __restrict__ xg, i8_t* __restrict__ xqg,
                                            float* __restrict__ rowfac, float2* __restrict__ ropetab) {
  int bid = blockIdx.x;
  if (bid < 4096) {
    int w = bid >> 10;
    double ssum = 0.0;
    for (int i = 0; i < 64; ++i) ssum += partial[w * 64 + i];
    float s = fmaxf((float)(ssum * (1.0 / 1048576.0)), 1e-5f);
    if ((bid & 1023) == 0 && threadIdx.x == 0) wscale[w] = s;
    const float* W = (w==0)?W0:(w==1)?W1:(w==2)?W2:W3;
    int off = ((bid & 1023) * 256 + threadIdx.x) * 4;
    float4 v = *(const float4*)(W + off);
    char4 q;
    q.x = (i8_t)(int)fminf(fmaxf(rintf(v.x / s), -1.f), 1.f);
    q.y = (i8_t)(int)fminf(fmaxf(rintf(v.y / s), -1.f), 1.f);
    q.z = (i8_t)(int)fminf(fmaxf(rintf(v.z / s), -1.f), 1.f);
    q.w = (i8_t)(int)fminf(fmaxf(rintf(v.w / s), -1.f), 1.f);
    *(char4*)(wq_all + (size_t)w * 1048576 + off) = q;
  } else if (bid < 8192) {
    int r = bid - 4096;
    float4 v = *(const float4*)(xg + (size_t)r * 1024 + threadIdx.x * 4);
    float mx = fmaxf(fmaxf(fabsf(v.x), fabsf(v.y)), fmaxf(fabsf(v.z), fabsf(v.w)));
    #pragma unroll
    for (int off = 1; off < 64; off <<= 1) mx = fmaxf(mx, __shfl_xor(mx, off));
    __shared__ float red[4];
    if ((threadIdx.x & 63) == 0) red[threadIdx.x >> 6] = mx;
    __syncthreads();
    mx = fmaxf(fmaxf(red[0], red[1]), fmaxf(red[2], red[3]));
    mx = fmaxf(mx, 1e-5f);
    float scale = 127.0f / mx;
    if (threadIdx.x == 0) rowfac[r] = mx * (1.0f / 127.0f);
    char4 q;
    q.x = (i8_t)(int)fminf(fmaxf(rintf(v.x * scale), -128.f), 127.f);
    q.y = (i8_t)(int)fminf(fmaxf(rintf(v.y * scale), -128.f), 127.f);
    q.z = (i8_t)(int)fminf(fmaxf(rintf(v.z * scale), -128.f), 127.f);
    q.w = (i8_t)(int)fminf(fmaxf(rintf(v.w * scale), -128.f), 127.f);
    *(char4*)(xqg + (size_t)r * 1024 + threadIdx.x * 4) = q;
  } else {
    int t = (bid - 8192) * 8 + (threadIdx.x >> 5);
    int ii = threadIdx.x & 31;
    float ang = (float)t * exp2f(-(float)ii * ROPE_C);
    float sn, cs;
    sincosf(ang, &sn, &cs);
    ropetab[t * 32 + ii] = make_float2(cs, sn);
  }
}

// ---- y-path act quant: combine bf16 parity partials (y0+y1)/(d0+d1), then row quant -> i8 ----
__global__ __launch_bounds__(256) void actquant(const bf16_t* __restrict__ yf0, const bf16_t* __restrict__ yf1,
                                                const float* __restrict__ den0, const float* __restrict__ den1,
                                                i8_t* __restrict__ xqg, float* __restrict__ rowfac) {
  int r = blockIdx.x;
  int b = r >> 11, t = r & 2047;
  int h = threadIdx.x >> 4;                       // (tid*4)>>6
  size_t idx = (size_t)r * 1024 + threadIdx.x * 4;
  bf16x4 u0 = *(const bf16x4*)(yf0 + idx);
  bf16x4 u1 = *(const bf16x4*)(yf1 + idx);
  size_t di = (size_t)(b * 16 + h) * 2048 + t;
  float inv = 1.0f / (den0[di] + den1[di]);
  float4 v;
  v.x = ((float)u0[0] + (float)u1[0]) * inv;
  v.y = ((float)u0[1] + (float)u1[1]) * inv;
  v.z = ((float)u0[2] + (float)u1[2]) * inv;
  v.w = ((float)u0[3] + (float)u1[3]) * inv;
  float mx = fmaxf(fmaxf(fabsf(v.x), fabsf(v.y)), fmaxf(fabsf(v.z), fabsf(v.w)));
  #pragma unroll
  for (int off = 1; off < 64; off <<= 1) mx = fmaxf(mx, __shfl_xor(mx, off));
  __shared__ float red[4];
  if ((threadIdx.x & 63) == 0) red[threadIdx.x >> 6] = mx;
  __syncthreads();
  mx = fmaxf(fmaxf(red[0], red[1]), fmaxf(red[2], red[3]));
  mx = fmaxf(mx, 1e-5f);
  float scale = 127.0f / mx;
  if (threadIdx.x == 0) rowfac[r] = mx * (1.0f / 127.0f);
  char4 q;
  q.x = (i8_t)(int)fminf(fmaxf(rintf(v.x * scale), -128.f), 127.f);
  q.y = (i8_t)(int)fminf(fmaxf(rintf(v.y * scale), -128.f), 127.f);
  q.z = (i8_t)(int)fminf(fmaxf(rintf(v.z * scale), -128.f), 127.f);
  q.w = (i8_t)(int)fminf(fmaxf(rintf(v.w * scale), -128.f), 127.f);
  *(char4*)(xqg + (size_t)r * 1024 + threadIdx.x * 4) = q;
}

// ---------------- QKV GEMM, i8 MFMA K=64: double-buffered 2-phase pipeline (R4-verified) ----------------
__global__ __launch_bounds__(256) void gemm_qkv(const i8_t* __restrict__ xq, const i8_t* __restrict__ wq_all,
                                                const float* __restrict__ wscale, const float* __restrict__ rowfac,
                                                const float2* __restrict__ ropetab,
                                                bf16_t* __restrict__ qb, bf16_t* __restrict__ kb,
                                                bf16_t* __restrict__ vtb) {
  const int z = blockIdx.z;
  const i8_t* Bw = wq_all + (size_t)z * 1048576;
  const int m0 = blockIdx.x * 128, n0 = blockIdx.y * 128;
  const int tid = threadIdx.x;
  const int wave = tid >> 6, lane = tid & 63, quad = lane >> 4, l16 = lane & 15;
  const int wm = wave >> 1, wn = wave & 1;
  __shared__ __align__(16) i8_t As[2][128 * 64];
  __shared__ __align__(16) i8_t Bs[2][128 * 64];
  i32x4 zero = {0, 0, 0, 0};
  i32x4 acc[4][4];
  #pragma unroll
  for (int i = 0; i < 4; ++i)
    #pragma unroll
    for (int j = 0; j < 4; ++j) acc[i][j] = zero;

  const int row_s = tid >> 2;
  const int cg16 = (((tid & 3) - (row_s >> 1)) & 3) * 16;   // swizzled global 16B-block (bytes)
  const int sw16 = ((quad + (l16 >> 1)) & 3) * 16;          // swizzled frag slot (bytes)

  // prologue: stage kt=0 into buffer 0
  #pragma unroll
  for (int v2 = 0; v2 < 2; ++v2) {
    int v = tid + v2 * 256;
    int row = row_s + v2 * 64;
    GLOAD_LDS(&xq[(size_t)(m0 + row) * 1024 + cg16], &As[0][v * 16]);
    GLOAD_LDS(&Bw[(size_t)(n0 + row) * 1024 + cg16], &Bs[0][v * 16]);
  }
  __syncthreads();   // drains vmcnt(0): buffer 0 ready

  #pragma unroll 2
  for (int kt = 0; kt < 16; ++kt) {
    const int cur = kt & 1;
    if (kt < 15) {
      #pragma unroll
      for (int v2 = 0; v2 < 2; ++v2) {
        int v = tid + v2 * 256;
        int row = row_s + v2 * 64;
        GLOAD_LDS(&xq[(size_t)(m0 + row) * 1024 + (kt + 1) * 64 + cg16], &As[cur ^ 1][v * 16]);
        GLOAD_LDS(&Bw[(size_t)(n0 + row) * 1024 + (kt + 1) * 64 + cg16], &Bs[cur ^ 1][v * 16]);
      }
    }
    i32x4 af[4], bfr[4];
    #pragma unroll
    for (int i = 0; i < 4; ++i) af[i] = *(const i32x4*)&As[cur][(wm * 64 + i * 16 + l16) * 64 + sw16];
    #pragma unroll
    for (int j = 0; j < 4; ++j) bfr[j] = *(const i32x4*)&Bs[cur][(wn * 64 + j * 16 + l16) * 64 + sw16];
    if (z == 2) {
      #pragma unroll
      for (int i = 0; i < 4; ++i)
        #pragma unroll
        for (int j = 0; j < 4; ++j) acc[i][j] = MFMAI8(bfr[i], af[j], acc[i][j]);  // C^T
    } else {
      #pragma unroll
      for (int i = 0; i < 4; ++i)
        #pragma unroll
        for (int j = 0; j < 4; ++j) acc[i][j] = MFMAI8(af[i], bfr[j], acc[i][j]);
    }
    __syncthreads();  // next-buffer loads drained; cur buffer free for kt+2 staging
  }
  float ws = wscale[z] * (z == 0 ? Q_PRESCALE : 1.0f);
  if (z <= 1) {
    bf16_t* dst = (z == 0) ? qb : kb;
    const int h = (n0 >> 6) + wn;
    #pragma unroll
    for (int i = 0; i < 4; ++i) {
      #pragma unroll
      for (int r = 0; r < 4; ++r) {
        int m = m0 + wm * 64 + i * 16 + quad * 4 + r;
        float rf = rowfac[m] * ws;
        int b = m >> 11, t = m & 2047;
        bf16_t* drow = dst + (((size_t)b * 16 + h) * 2048 + t) * 64;
        #pragma unroll
        for (int j = 0; j < 2; ++j) {
          int dd1 = j * 16 + l16;
          float2 cs2 = ropetab[t * 32 + dd1];
          float v1 = (float)acc[i][j][r] * rf;
          float v2 = (float)acc[i][j + 2][r] * rf;
          drow[dd1]      = (bf16_t)(v1 * cs2.x - v2 * cs2.y);
          drow[dd1 + 32] = (bf16_t)(v1 * cs2.y + v2 * cs2.x);
        }
      }
    }
  } else {
    // acc is C^T: row = n (head dim), col = m (time)
    const int b = m0 >> 11;
    const int tbase = (m0 & 2047) + wm * 64;
    float rfj[4];
    #pragma unroll
    for (int j = 0; j < 4; ++j) rfj[j] = rowfac[m0 + wm * 64 + j * 16 + l16] * ws;
    #pragma unroll
    for (int i = 0; i < 4; ++i) {
      #pragma unroll
      for (int r = 0; r < 4; ++r) {
        int nrow = n0 + wn * 64 + i * 16 + quad * 4 + r;
        int h = nrow >> 6, dd = nrow & 63;
        bf16_t* vrow = vtb + (((size_t)b * 16 + h) * 64 + dd) * 2048 + tbase;
        #pragma unroll
        for (int j = 0; j < 4; ++j) vrow[j * 16 + l16] = (bf16_t)((float)acc[i][j][r] * rfj[j]);
      }
    }
  }
}

// ---------------- output GEMM (i8 MFMA, 2-phase pipeline) -> d_out (float32) ----------------
__global__ __launch_bounds__(256) void gemm_out(const i8_t* __restrict__ yq, const i8_t* __restrict__ wo,
                                                const float* __restrict__ wscale, const float* __restrict__ rowfac,
                                                float* __restrict__ out) {
  const int m0 = blockIdx.x * 128, n0 = blockIdx.y * 128;
  const int tid = threadIdx.x;
  const int wave = tid >> 6, lane = tid & 63, quad = lane >> 4, l16 = lane & 15;
  const int wm = wave >> 1, wn = wave & 1;
  __shared__ __align__(16) i8_t As[2][128 * 64];
  __shared__ __align__(16) i8_t Bs[2][128 * 64];
  i32x4 zero = {0, 0, 0, 0};
  i32x4 acc[4][4];
  #pragma unroll
  for (int i = 0; i < 4; ++i)
    #pragma unroll
    for (int j = 0; j < 4; ++j) acc[i][j] = zero;

  const int row_s = tid >> 2;
  const int cg16 = (((tid & 3) - (row_s >> 1)) & 3) * 16;
  const int sw16 = ((quad + (l16 >> 1)) & 3) * 16;

  #pragma unroll
  for (int v2 = 0; v2 < 2; ++v2) {
    int v = tid + v2 * 256;
    int row = row_s + v2 * 64;
    GLOAD_LDS(&yq[(size_t)(m0 + row) * 1024 + cg16], &As[0][v * 16]);
    GLOAD_LDS(&wo[(size_t)(n0 + row) * 1024 + cg16], &Bs[0][v * 16]);
  }
  __syncthreads();

  #pragma unroll 2
  for (int kt = 0; kt < 16; ++kt) {
    const int cur = kt & 1;
    if (kt < 15) {
      #pragma unroll
      for (int v2 = 0; v2 < 2; ++v2) {
        int v = tid + v2 * 256;
        int row = row_s + v2 * 64;
        GLOAD_LDS(&yq[(size_t)(m0 + row) * 1024 + (kt + 1) * 64 + cg16], &As[cur ^ 1][v * 16]);
        GLOAD_LDS(&wo[(size_t)(n0 + row) * 1024 + (kt + 1) * 64 + cg16], &Bs[cur ^ 1][v * 16]);
      }
    }
    i32x4 af[4], bfr[4];
    #pragma unroll
    for (int i = 0; i < 4; ++i) af[i] = *(const i32x4*)&As[cur][(wm * 64 + i * 16 + l16) * 64 + sw16];
    #pragma unroll
    for (int j = 0; j < 4; ++j) bfr[j] = *(const i32x4*)&Bs[cur][(wn * 64 + j * 16 + l16) * 64 + sw16];
    #pragma unroll
    for (int i = 0; i < 4; ++i)
      #pragma unroll
      for (int j = 0; j < 4; ++j) acc[i][j] = MFMAI8(af[i], bfr[j], acc[i][j]);
    __syncthreads();
  }
  float ws = wscale[3];
  #pragma unroll
  for (int i = 0; i < 4; ++i) {
    #pragma unroll
    for (int r = 0; r < 4; ++r) {
      int m = m0 + wm * 64 + i * 16 + quad * 4 + r;
      float rf = rowfac[m] * ws;
      #pragma unroll
      for (int j = 0; j < 4; ++j) {
        int n = n0 + wn * 64 + j * 16 + l16;
        out[(size_t)m * 1024 + n] = (float)acc[i][j][r] * rf;
      }
    }
  }
}

// ---------------- flash attention: parity-split kc, 512 duration-uniform blocks ----------------
// Numerator partials stored as bf16 (same exponent range as f32 - no overflow risk; the
// 2^-9 mantissa loss is far below actquant's 1/127 quant granularity).
__global__ __launch_bounds__(512) void flash_attn(const bf16_t* __restrict__ qg, const bf16_t* __restrict__ kg,
                                                  const bf16_t* __restrict__ vtg,
                                                  bf16_t* __restrict__ yf0, bf16_t* __restrict__ yf1,
                                                  float* __restrict__ den0, float* __restrict__ den1) {
  const int lid = (int)blockIdx.y * 8 + (int)blockIdx.x;  // 0..511
  const int par = (lid >> 3) & 1;
  const int p   = (lid >> 4) & 7;
  const int bh  = (lid & 7) * 4 + (lid >> 7);
  bf16_t* __restrict__ yo = par ? yf1 : yf0;
  float* __restrict__ dn = par ? den1 : den0;
  const int tid = threadIdx.x;        // 0..511
  const int wave = tid >> 6, lane = tid & 63;
  const int quad = lane >> 4, l16 = lane & 15;

  __shared__ __align__(16) bf16_t Kb[2][64 * 64];
  __shared__ __align__(16) bf16_t Vb[2][64 * 64];
  __shared__ __align__(16) bf16_t Pl[8][16 * 72];

  const int b = bh >> 4, h = bh & 15;
  bf16_t* Pw = &Pl[wave][0];

  const int r0 = tid >> 3, cblk = tid & 7;
  const int ldsOff0 = r0 * 64 + ((cblk ^ (r0 & 7)) * 8);
  const size_t bhbase = (size_t)bh * 131072;
  const bf16_t* kbase0 = kg + bhbase + r0 * 64 + cblk * 8;    // + kc*4096
  const bf16_t* vbase0 = vtg + bhbase + r0 * 2048 + cblk * 8; // + kc*64

  int kf_off[4][2];
  #pragma unroll
  for (int n = 0; n < 4; ++n)
    #pragma unroll
    for (int c = 0; c < 2; ++c)
      kf_off[n][c] = (n * 16 + l16) * 64 + (((c * 4 + quad) ^ (l16 & 7)) * 8);

  bf16x8 ones;
  #pragma unroll
  for (int j = 0; j < 8; ++j) ones[j] = (bf16_t)1.0f;
  f32x4 zero = {0.f, 0.f, 0.f, 0.f};

  bf16x8 kpre = *(const bf16x8*)(kbase0 + par * 4096);
  bf16x8 vpre = *(const bf16x8*)(vbase0 + par * 64);

  int cum = 0;
  #pragma unroll 1
  for (int tsel = 0; tsel < 2; ++tsel) {
    const int qt = tsel ? (15 - p) : p;
    const int kcmax = 2 * qt + 1;                 // par <= kcmax always (kcmax >= 1)
    const int qbw = qt * 128 + wave * 16;

    const bf16_t* qrowp = qg + ((size_t)bh * TSEQ + qbw + l16) * 64;
    bf16x8 aq0 = *(const bf16x8*)(qrowp + quad * 8);
    bf16x8 aq1 = *(const bf16x8*)(qrowp + 32 + quad * 8);

    f32x4 o[4], o5;
    #pragma unroll
    for (int i = 0; i < 4; ++i) o[i] = zero;
    o5 = zero;

    #pragma unroll 1
    for (int kc = par; kc <= kcmax; kc += 2, ++cum) {
      const int buf = cum & 1;
      bf16_t* Kt = &Kb[buf][0];
      bf16_t* Vt = &Vb[buf][0];
      *(bf16x8*)&Kt[ldsOff0] = kpre;
      *(bf16x8*)&Vt[ldsOff0] = vpre;
      __syncthreads();
      int nkc = (kc + 2 <= kcmax) ? (kc + 2) : ((tsel == 0) ? par : -1);
      if (nkc >= 0) {
        kpre = *(const bf16x8*)(kbase0 + nkc * 4096);
        vpre = *(const bf16x8*)(vbase0 + nkc * 64);
      }

      // wave's 16 q-rows entirely below this k-chunk: contribution is exactly zero.
      if (kc * 64 > qbw + 15) continue;

      f32x4 s[4];
      __builtin_amdgcn_s_setprio(1);
      #pragma unroll
      for (int n = 0; n < 4; ++n) {
        bf16x8 bk0 = *(const bf16x8*)&Kt[kf_off[n][0]];
        bf16x8 bk1 = *(const bf16x8*)&Kt[kf_off[n][1]];
        s[n] = MFMA16(aq1, bk1, MFMA16(aq0, bk0, zero));
      }
      __builtin_amdgcn_s_setprio(0);
      if (kc * 64 + 63 > qbw) {
        #pragma unroll
        for (int n = 0; n < 4; ++n)
          #pragma unroll
          for (int r = 0; r < 4; ++r) {
            int kpos = kc * 64 + n * 16 + l16;
            int qpos = qbw + quad * 4 + r;
            if (kpos > qpos) s[n][r] = NEG_BIG;
          }
      }
      #pragma unroll
      for (int n = 0; n < 4; ++n)
        #pragma unroll
        for (int r = 0; r < 4; ++r)
          Pw[(quad * 4 + r) * 72 + n * 16 + l16] = (bf16_t)EXP2F(s[n][r]);

      bf16x8 ap0 = *(const bf16x8*)&Pw[l16 * 72 + quad * 8];
      bf16x8 ap1 = *(const bf16x8*)&Pw[l16 * 72 + 32 + quad * 8];
      __builtin_amdgcn_s_setprio(1);
      #pragma unroll
      for (int nh = 0; nh < 4; ++nh) {
        bf16x8 bv0 = *(const bf16x8*)&Vt[kf_off[nh][0]];
        bf16x8 bv1 = *(const bf16x8*)&Vt[kf_off[nh][1]];
        o[nh] = MFMA16(ap1, bv1, MFMA16(ap0, bv0, o[nh]));
      }
      o5 = MFMA16(ap1, ones, MFMA16(ap0, ones, o5));
      __builtin_amdgcn_s_setprio(0);
    }

    // write un-normalized partial numerator (bf16) + denominator (f32) for this parity
    #pragma unroll
    for (int r = 0; r < 4; ++r) {
      int t = qbw + quad * 4 + r;
      bf16_t* yrow = yo + ((size_t)b * TSEQ + t) * CDIM + h * 64;
      #pragma unroll
      for (int nh = 0; nh < 4; ++nh) yrow[nh * 16 + l16] = (bf16_t)o[nh][r];
      if (l16 == 0) dn[(size_t)bh * TSEQ + t] = o5[r];
    }
  }
}

extern "C" void kernel_launch(void* const* d_in, const int* in_sizes, int n_in,
                              void* d_out, int out_size, void* d_ws, size_t ws_size,
                              hipStream_t stream) {
  const float* x  = (const float*)d_in[0];
  const float* Wq = (const float*)d_in[1];
  const float* Wk = (const float*)d_in[2];
  const float* Wv = (const float*)d_in[3];
  const float* Wo = (const float*)d_in[4];
  float* out = (float*)d_out;   // reference output dtype is float32

  char* ws = (char*)d_ws;
  double* wpartial = (double*)(ws);                  // 256 f64
  float* wscale   = (float*)(ws + 4096);             // 4 f32
  float* rowfacx  = (float*)(ws + 8192);             // 4096 f32
  float* rowfacy  = (float*)(ws + 8192 + 16384);     // 4096 f32
  i8_t* wq_all    = (i8_t*)(ws + 65536);             // 4M i8 = 4MB
  i8_t* xq        = wq_all + 4194304;                // 4MB (aliased as yq later)
  bf16_t* qb      = (bf16_t*)(xq + 4194304);         // 8MB
  bf16_t* kb      = qb + 4194304;                    // 8MB
  bf16_t* vtb     = kb + 4194304;                    // 8MB, d-major V
  bf16_t* yf0     = vtb + 4194304;                   // 8MB (even-parity numerator, bf16)
  bf16_t* yf1     = yf0 + 4194304;                   // 8MB (odd-parity numerator, bf16)
  float2* ropetab = (float2*)(yf1 + 4194304);        // 512KB
  float*  den0    = (float*)((char*)ropetab + 524288); // 256KB
  float*  den1    = den0 + 65536;                    // 256KB
  i8_t* yq        = xq;                              // alias: xq dead after gemm_qkv

  wreduce<<<256, 256, 0, stream>>>(Wq, Wk, Wv, Wo, wpartial);
  prep<<<8448, 256, 0, stream>>>(Wq, Wk, Wv, Wo, wpartial, wscale, wq_all, x, xq, rowfacx, ropetab);
  gemm_qkv<<<dim3(32, 8, 3), 256, 0, stream>>>(xq, wq_all, wscale, rowfacx, ropetab, qb, kb, vtb);
  flash_attn<<<dim3(8, 64), 512, 0, stream>>>(qb, kb, vtb, yf0, yf1, den0, den1);
  actquant<<<4096, 256, 0, stream>>>(yf0, yf1, den0, den1, yq, rowfacy);
  gemm_out<<<dim3(32, 8), 256, 0, stream>>>(yq, wq_all + 3 * 1048576, wscale, rowfacy, out);
}